// Round 1
// baseline (458.013 us; speedup 1.0000x reference)
//
#include <hip/hip_runtime.h>
#include <hip/hip_bf16.h>

// Problem constants
constexpr int NV = 1024;   // vocab
constexpr int NH = 8;      // heads
constexpr int NB = 8;      // batch
constexpr int NT = 1024;   // seq len
constexpr int ND = NV * NH; // 8192 = value dim

typedef __bf16 bf16x8 __attribute__((ext_vector_type(8)));
typedef float f32x4 __attribute__((ext_vector_type(4)));

// ---------------- histogram: cnt[b][v] = #positions in batch b with token v ----
__global__ __launch_bounds__(256) void hist_kernel(const int* __restrict__ tok,
                                                   int* __restrict__ cnt) {
    int idx = blockIdx.x * 256 + threadIdx.x;   // 0 .. NB*NT-1
    int b = idx >> 10;
    int t = tok[idx];
    atomicAdd(&cnt[(b << 10) + t], 1);
}

// ---------------- W'[b][t][u] = cnt_b[u]*exp(h[t][u])/Z + (u==t), bf16 ---------
__global__ __launch_bounds__(256) void wprime_kernel(const float* __restrict__ h,
                                                     const int* __restrict__ cnt,
                                                     __hip_bfloat16* __restrict__ wp) {
    int bt = blockIdx.x;                 // b*1024 + t
    int b = bt >> 10, t = bt & 1023;
    const float* hrow = h + (size_t)t * NV;
    const int* crow = cnt + (b << 10);
    float e[4];
    float s = 0.f;
#pragma unroll
    for (int i = 0; i < 4; ++i) {
        int u = threadIdx.x + 256 * i;
        e[i] = __expf(hrow[u]) * (float)crow[u];
        s += e[i];
    }
#pragma unroll
    for (int off = 32; off > 0; off >>= 1) s += __shfl_down(s, off, 64);
    __shared__ float wsum[4];
    if ((threadIdx.x & 63) == 0) wsum[threadIdx.x >> 6] = s;
    __syncthreads();
    float Z = wsum[0] + wsum[1] + wsum[2] + wsum[3];
    float rz = 1.0f / Z;
#pragma unroll
    for (int i = 0; i < 4; ++i) {
        int u = threadIdx.x + 256 * i;
        float w = e[i] * rz + (u == t ? 1.0f : 0.0f);
        wp[(size_t)bt * NV + u] = __float2bfloat16(w);
    }
}

// ---------------- vwT[d][k] = (bf16) vw[k][d]  (ND x NV) ------------------------
__global__ __launch_bounds__(256) void tcast_kernel(const float* __restrict__ vw,
                                                    __hip_bfloat16* __restrict__ vwT) {
    __shared__ float tile[32][33];
    int k0 = blockIdx.x * 32;
    int d0 = blockIdx.y * 32;
    int tx = threadIdx.x & 31;
    int ty = threadIdx.x >> 5;   // 0..7
#pragma unroll
    for (int s = 0; s < 4; ++s)
        tile[ty + 8 * s][tx] = vw[(size_t)(k0 + ty + 8 * s) * ND + d0 + tx];
    __syncthreads();
#pragma unroll
    for (int s = 0; s < 4; ++s)
        vwT[(size_t)(d0 + ty + 8 * s) * NV + k0 + tx] =
            __float2bfloat16(tile[tx][ty + 8 * s]);
}

// ---------------- GEMM: out[b][i][:] = (W'_b @ vw)[tok[b][i]][:] ----------------
// 128x128 tile, BK=32, 4 waves (2x2), 16x16x32 bf16 MFMA, global_load_lds,
// XOR-swizzled LDS (slot c holds source col-block c ^ ((row>>1)&3)).
__global__ __launch_bounds__(256) void gemm_kernel(
    const __hip_bfloat16* __restrict__ wp,    // [NB][NV][NV]
    const __hip_bfloat16* __restrict__ vwT,   // [ND][NV]
    const int* __restrict__ tok,              // [NB][NT]
    float* __restrict__ out) {                // [NB][NT][ND]
    __shared__ __align__(16) __hip_bfloat16 As[128 * 32];
    __shared__ __align__(16) __hip_bfloat16 Bs[128 * 32];

    int blk = blockIdx.x;
    int b = blk >> 9;          // 512 tiles per batch
    int rem = blk & 511;
    int bm = rem >> 6;         // 0..7  (rows of out, 128 each)
    int bn = rem & 63;         // 0..63 (cols, 128 each)
    int i0 = bm << 7;
    int n0 = bn << 7;
    int tid = threadIdx.x;

    // staging: 512 16B segments per tile; thread tid handles seg tid and tid+256
    int rw0 = tid >> 2;        // 0..63
    int c0 = tid & 3;
    int rw1 = rw0 + 64;
    int cs0 = c0 ^ ((rw0 >> 1) & 3);
    int cs1 = c0 ^ ((rw1 >> 1) & 3);
    int tk0 = tok[(b << 10) + i0 + rw0];
    int tk1 = tok[(b << 10) + i0 + rw1];
    const __hip_bfloat16* srcA0 = wp + (((size_t)(b << 10) + tk0) << 10) + (cs0 << 3);
    const __hip_bfloat16* srcA1 = wp + (((size_t)(b << 10) + tk1) << 10) + (cs1 << 3);
    const __hip_bfloat16* srcB0 = vwT + ((size_t)(n0 + rw0) << 10) + (cs0 << 3);
    const __hip_bfloat16* srcB1 = vwT + ((size_t)(n0 + rw1) << 10) + (cs1 << 3);

    int lane = tid & 63;
    int wave = tid >> 6;
    int wm = wave >> 1, wn = wave & 1;
    int quad = lane >> 4;
    int l15 = lane & 15;
    int offA[4], offB[4];
#pragma unroll
    for (int f = 0; f < 4; ++f) {
        int m = (wm << 6) + (f << 4) + l15;
        offA[f] = (m << 5) + ((quad ^ ((m >> 1) & 3)) << 3);
        int n = (wn << 6) + (f << 4) + l15;
        offB[f] = (n << 5) + ((quad ^ ((n >> 1) & 3)) << 3);
    }

    f32x4 acc[4][4];
#pragma unroll
    for (int i = 0; i < 4; ++i)
#pragma unroll
        for (int j = 0; j < 4; ++j)
            acc[i][j] = (f32x4){0.f, 0.f, 0.f, 0.f};

    for (int k0 = 0; k0 < NV; k0 += 32) {
        __builtin_amdgcn_global_load_lds(
            (const __attribute__((address_space(1))) void*)srcA0,
            (__attribute__((address_space(3))) void*)(As + (tid << 3)), 16, 0, 0);
        __builtin_amdgcn_global_load_lds(
            (const __attribute__((address_space(1))) void*)srcA1,
            (__attribute__((address_space(3))) void*)(As + ((tid + 256) << 3)), 16, 0, 0);
        __builtin_amdgcn_global_load_lds(
            (const __attribute__((address_space(1))) void*)srcB0,
            (__attribute__((address_space(3))) void*)(Bs + (tid << 3)), 16, 0, 0);
        __builtin_amdgcn_global_load_lds(
            (const __attribute__((address_space(1))) void*)srcB1,
            (__attribute__((address_space(3))) void*)(Bs + ((tid + 256) << 3)), 16, 0, 0);
        srcA0 += 32; srcA1 += 32; srcB0 += 32; srcB1 += 32;
        __syncthreads();
        bf16x8 af[4], bf[4];
#pragma unroll
        for (int f = 0; f < 4; ++f) {
            af[f] = *(const bf16x8*)(As + offA[f]);
            bf[f] = *(const bf16x8*)(Bs + offB[f]);
        }
#pragma unroll
        for (int i = 0; i < 4; ++i)
#pragma unroll
            for (int j = 0; j < 4; ++j)
                acc[i][j] = __builtin_amdgcn_mfma_f32_16x16x32_bf16(af[i], bf[j],
                                                                    acc[i][j], 0, 0, 0);
        __syncthreads();
    }

    // epilogue: C/D layout col=lane&15, row=quad*4+reg
    size_t outbase = (((size_t)(b << 10) + i0) << 13) + n0;
#pragma unroll
    for (int fi = 0; fi < 4; ++fi) {
#pragma unroll
        for (int fj = 0; fj < 4; ++fj) {
            int r0 = (wm << 6) + (fi << 4) + (quad << 2);
            int cc = (wn << 6) + (fj << 4) + l15;
            float* po = out + outbase + ((size_t)r0 << 13) + cc;
#pragma unroll
            for (int r = 0; r < 4; ++r)
                po[(size_t)r << 13] = acc[fi][fj][r];
        }
    }
}

extern "C" void kernel_launch(void* const* d_in, const int* in_sizes, int n_in,
                              void* d_out, int out_size, void* d_ws, size_t ws_size,
                              hipStream_t stream) {
    const int* tok = (const int*)d_in[0];       // [NB][NT] token ids
    const float* h = (const float*)d_in[1];     // [NV][NV]
    const float* vw = (const float*)d_in[2];    // [NV][ND]
    float* out = (float*)d_out;                 // [NB][NT][ND]

    char* ws = (char*)d_ws;
    int* cnt = (int*)ws;                                          // 32 KB
    __hip_bfloat16* wp = (__hip_bfloat16*)(ws + (1 << 16));       // 16 MB
    __hip_bfloat16* vwT = (__hip_bfloat16*)(ws + (1 << 16) +
                                            (size_t)NB * NV * NV * 2); // 16 MB

    hipMemsetAsync(cnt, 0, NB * NV * sizeof(int), stream);
    hist_kernel<<<NB * NT / 256, 256, 0, stream>>>(tok, cnt);
    wprime_kernel<<<NB * NV, 256, 0, stream>>>(h, cnt, wp);
    tcast_kernel<<<dim3(NV / 32, ND / 32), 256, 0, stream>>>(vw, vwT);
    gemm_kernel<<<NB * (NT / 128) * (ND / 128), 256, 0, stream>>>(wp, vwT, tok, out);
}

// Round 3
// 425.816 us; speedup vs baseline: 1.0756x; 1.0756x over previous
//
#include <hip/hip_runtime.h>
#include <hip/hip_bf16.h>

// Problem constants
constexpr int NV = 1024;   // vocab
constexpr int NH = 8;      // heads
constexpr int NB = 8;      // batch
constexpr int NT = 1024;   // seq len
constexpr int ND = NV * NH; // 8192 = value dim

typedef __bf16 bf16x8 __attribute__((ext_vector_type(8)));
typedef __bf16 bf16x4 __attribute__((ext_vector_type(4)));
typedef float f32x4 __attribute__((ext_vector_type(4)));

// ---------------- histogram: cnt[b][v] = #positions in batch b with token v ----
__global__ __launch_bounds__(256) void hist_kernel(const int* __restrict__ tok,
                                                   int* __restrict__ cnt) {
    int idx = blockIdx.x * 256 + threadIdx.x;   // 0 .. NB*NT-1
    int b = idx >> 10;
    int t = tok[idx];
    atomicAdd(&cnt[(b << 10) + t], 1);
}

// ---------------- W'[b][t][u] = cnt_b[u]*exp(h[t][u])/Z + (u==t), bf16 ---------
// Vectorized: float4/int4 loads, 8B packed bf16x4 stores.
__global__ __launch_bounds__(256) void wprime_kernel(const float* __restrict__ h,
                                                     const int* __restrict__ cnt,
                                                     __bf16* __restrict__ wp) {
    int bt = blockIdx.x;                 // b*1024 + t
    int b = bt >> 10, t = bt & 1023;
    const float4* hrow = (const float4*)(h + (size_t)t * NV);
    const int4* crow = (const int4*)(cnt + (b << 10));
    float4 hv = hrow[threadIdx.x];
    int4 cv = crow[threadIdx.x];
    float e0 = __expf(hv.x) * (float)cv.x;
    float e1 = __expf(hv.y) * (float)cv.y;
    float e2 = __expf(hv.z) * (float)cv.z;
    float e3 = __expf(hv.w) * (float)cv.w;
    float s = (e0 + e1) + (e2 + e3);
#pragma unroll
    for (int off = 32; off > 0; off >>= 1) s += __shfl_down(s, off, 64);
    __shared__ float wsum[4];
    if ((threadIdx.x & 63) == 0) wsum[threadIdx.x >> 6] = s;
    __syncthreads();
    float rz = 1.0f / (wsum[0] + wsum[1] + wsum[2] + wsum[3]);
    int u0 = threadIdx.x << 2;
    float w0 = e0 * rz + (u0 + 0 == t ? 1.0f : 0.0f);
    float w1 = e1 * rz + (u0 + 1 == t ? 1.0f : 0.0f);
    float w2 = e2 * rz + (u0 + 2 == t ? 1.0f : 0.0f);
    float w3 = e3 * rz + (u0 + 3 == t ? 1.0f : 0.0f);
    bf16x4 pk = {(__bf16)w0, (__bf16)w1, (__bf16)w2, (__bf16)w3};
    *(bf16x4*)(wp + (size_t)bt * NV + u0) = pk;
}

// ---------------- vwT[d][k] = (bf16) vw[k][d]  (ND x NV) ------------------------
__global__ __launch_bounds__(256) void tcast_kernel(const float* __restrict__ vw,
                                                    __bf16* __restrict__ vwT) {
    __shared__ float tile[32][33];
    int k0 = blockIdx.x * 32;
    int d0 = blockIdx.y * 32;
    int tx = threadIdx.x & 31;
    int ty = threadIdx.x >> 5;   // 0..7
#pragma unroll
    for (int s = 0; s < 4; ++s)
        tile[ty + 8 * s][tx] = vw[(size_t)(k0 + ty + 8 * s) * ND + d0 + tx];
    __syncthreads();
#pragma unroll
    for (int s = 0; s < 4; ++s)
        vwT[(size_t)(d0 + ty + 8 * s) * NV + k0 + tx] =
            (__bf16)tile[tx][ty + 8 * s];
}

// ---------------- GEMM: out[b][i][:] = (W'_b @ vw)[tok[b][i]][:] ----------------
// 128x128 tile, BK=64 (two 16-MFMA phases per barrier pair), 4 waves (2x2),
// 16x16x32 bf16 MFMA, global_load_lds width=16.
// LDS layout: 128 rows x 8 chunks of 8 bf16; physical chunk c holds source
// chunk c ^ (row&7)  ->  ds_read_b128 fragment reads are 2-way (free).
__global__ __launch_bounds__(256) void gemm_kernel(
    const __bf16* __restrict__ wp,    // [NB][NV][NV]
    const __bf16* __restrict__ vwT,   // [ND][NV]
    const int* __restrict__ tok,      // [NB][NT]
    float* __restrict__ out) {        // [NB][NT][ND]
    __shared__ __align__(16) __bf16 As[128 * 64];
    __shared__ __align__(16) __bf16 Bs[128 * 64];

    int blk = blockIdx.x;
    int b = blk >> 9;          // 512 tiles per batch
    int rem = blk & 511;
    int bm = rem >> 6;         // 0..7  (rows of out, 128 each)
    int bn = rem & 63;         // 0..63 (cols, 128 each)
    int i0 = bm << 7;
    int n0 = bn << 7;
    int tid = threadIdx.x;

    // staging: 1024 16B segments per matrix per iter; thread handles segments
    // tid + 256*p, p=0..3.  seg s -> row s>>3, physical chunk s&7.
    int r0 = tid >> 3;          // 0..31
    int c = tid & 7;
    int cs = c ^ (r0 & 7);      // source chunk; rows step by 32 so (r&7) const
    const __bf16* srcA[4];
#pragma unroll
    for (int p = 0; p < 4; ++p) {
        int r = r0 + 32 * p;
        int tk = tok[(b << 10) + i0 + r];
        srcA[p] = wp + (((size_t)(b << 10) + tk) << 10) + (cs << 3);
    }
    const __bf16* srcB = vwT + ((size_t)(n0 + r0) << 10) + (cs << 3);

    int lane = tid & 63;
    int wave = tid >> 6;
    int wm = wave >> 1, wn = wave & 1;
    int quad = lane >> 4;
    int l15 = lane & 15;
    int offA[4], offB[4];       // h=0 offsets; h=1 is off ^ 32
#pragma unroll
    for (int f = 0; f < 4; ++f) {
        int m = (wm << 6) + (f << 4) + l15;
        offA[f] = (m << 6) + (((quad) ^ (m & 7)) << 3);
        int n = (wn << 6) + (f << 4) + l15;
        offB[f] = (n << 6) + (((quad) ^ (n & 7)) << 3);
    }

    f32x4 acc[4][4];
#pragma unroll
    for (int i = 0; i < 4; ++i)
#pragma unroll
        for (int j = 0; j < 4; ++j)
            acc[i][j] = (f32x4){0.f, 0.f, 0.f, 0.f};

    for (int k0 = 0; k0 < NV; k0 += 64) {
#pragma unroll
        for (int p = 0; p < 4; ++p) {
            __builtin_amdgcn_global_load_lds(
                (const __attribute__((address_space(1))) void*)srcA[p],
                (__attribute__((address_space(3))) void*)(As + ((tid + 256 * p) << 3)),
                16, 0, 0);
            __builtin_amdgcn_global_load_lds(
                (const __attribute__((address_space(1))) void*)(srcB + (p << 15)),
                (__attribute__((address_space(3))) void*)(Bs + ((tid + 256 * p) << 3)),
                16, 0, 0);
            srcA[p] += 64;
        }
        srcB += 64;
        __syncthreads();
        // phase h=0 (k 0..31 of this tile)
        {
            bf16x8 af[4], bf[4];
#pragma unroll
            for (int f = 0; f < 4; ++f) {
                af[f] = *(const bf16x8*)(As + offA[f]);
                bf[f] = *(const bf16x8*)(Bs + offB[f]);
            }
#pragma unroll
            for (int i = 0; i < 4; ++i)
#pragma unroll
                for (int j = 0; j < 4; ++j)
                    acc[i][j] = __builtin_amdgcn_mfma_f32_16x16x32_bf16(
                        af[i], bf[j], acc[i][j], 0, 0, 0);
        }
        // phase h=1 (k 32..63): source chunk q|4  ->  physical offset ^ 32 elems
        {
            bf16x8 af[4], bf[4];
#pragma unroll
            for (int f = 0; f < 4; ++f) {
                af[f] = *(const bf16x8*)(As + (offA[f] ^ 32));
                bf[f] = *(const bf16x8*)(Bs + (offB[f] ^ 32));
            }
#pragma unroll
            for (int i = 0; i < 4; ++i)
#pragma unroll
                for (int j = 0; j < 4; ++j)
                    acc[i][j] = __builtin_amdgcn_mfma_f32_16x16x32_bf16(
                        af[i], bf[j], acc[i][j], 0, 0, 0);
        }
        __syncthreads();
    }

    // epilogue: C/D layout col=lane&15, row=quad*4+reg
    size_t outbase = (((size_t)(b << 10) + i0) << 13) + n0;
#pragma unroll
    for (int fi = 0; fi < 4; ++fi) {
#pragma unroll
        for (int fj = 0; fj < 4; ++fj) {
            int rr0 = (wm << 6) + (fi << 4) + (quad << 2);
            int cc = (wn << 6) + (fj << 4) + l15;
            float* po = out + outbase + ((size_t)rr0 << 13) + cc;
#pragma unroll
            for (int r = 0; r < 4; ++r)
                po[(size_t)r << 13] = acc[fi][fj][r];
        }
    }
}

extern "C" void kernel_launch(void* const* d_in, const int* in_sizes, int n_in,
                              void* d_out, int out_size, void* d_ws, size_t ws_size,
                              hipStream_t stream) {
    const int* tok = (const int*)d_in[0];       // [NB][NT] token ids
    const float* h = (const float*)d_in[1];     // [NV][NV]
    const float* vw = (const float*)d_in[2];    // [NV][ND]
    float* out = (float*)d_out;                 // [NB][NT][ND]

    char* ws = (char*)d_ws;
    int* cnt = (int*)ws;                                    // 32 KB
    __bf16* wp = (__bf16*)(ws + (1 << 16));                 // 16 MB
    __bf16* vwT = (__bf16*)(ws + (1 << 16) +
                            (size_t)NB * NV * NV * 2);      // 16 MB

    (void)hipMemsetAsync(cnt, 0, NB * NV * sizeof(int), stream);
    hist_kernel<<<NB * NT / 256, 256, 0, stream>>>(tok, cnt);
    wprime_kernel<<<NB * NV, 256, 0, stream>>>(h, cnt, wp);
    tcast_kernel<<<dim3(NV / 32, ND / 32), 256, 0, stream>>>(vw, vwT);
    gemm_kernel<<<NB * (NT / 128) * (ND / 128), 256, 0, stream>>>(wp, vwT, tok, out);
}